// Round 11
// baseline (344.107 us; speedup 1.0000x reference)
//
#include <hip/hip_runtime.h>
#include <math.h>

#define HDIM 512
#define NROWS 100000
#define NBLK_A 2048
#define K_CAP 1024           // max survivors finale holds (data: ~3)

// ---- workspace layout (float indices) ----
constexpr int BMIN_OFF   = 0;                        // [NBLK_A] per-block min ||K-cue||^2
constexpr int CNTL_OFF   = NBLK_A;                   // [NBLK_A] int candidate counts
constexpr int CAND_OFF   = 2 * NBLK_A;               // [NBLK_A*64] float2 {ss, idx}
constexpr int PREACT_OFF = CAND_OFF + NBLK_A * 128;  // [5*HDIM]
constexpr int TICK_OFF   = PREACT_OFF + 5 * HDIM;    // [1] int ticket (memset 0)

__device__ __forceinline__ float wave_sum(float v) {
    #pragma unroll
    for (int off = 32; off; off >>= 1) v += __shfl_xor(v, off);
    return v;
}
__device__ __forceinline__ float wave_min(float v) {
    #pragma unroll
    for (int off = 32; off; off >>= 1) v = fminf(v, __shfl_xor(v, off));
    return v;
}
__device__ __forceinline__ float d2sum(float4 a, float4 c) {
    float d, s;
    d = a.x - c.x; s  = d * d;
    d = a.y - c.y; s += d * d;
    d = a.z - c.z; s += d * d;
    d = a.w - c.w; s += d * d;
    return s;
}

// ===== fused: R10 sweep (no sims store) + no-poll last-block finale ==========
__global__ __launch_bounds__(256)
void kF(const float* __restrict__ state, const float* __restrict__ pa,
        const float* __restrict__ pr, const float* __restrict__ ts,
        const float* __restrict__ cue, const float* __restrict__ K,
        const float* __restrict__ V, const float* __restrict__ Wx,
        const float* __restrict__ Wh, const float* __restrict__ b,
        const float* __restrict__ aw, const float* __restrict__ ab,
        const float* __restrict__ cw, const float* __restrict__ cb,
        const float* __restrict__ h0, const float* __restrict__ c0,
        float* __restrict__ ws, float* __restrict__ out) {
    const int lane = threadIdx.x & 63;
    const int wib  = threadIdx.x >> 6;
    const int gw   = blockIdx.x * 4 + wib;
    const int nw   = NBLK_A * 4;                 // 8192 waves

    // ---- preact rows (first 2560 waves; hides under the BW-bound sweep) ----
    if (gw < 5 * HDIM) {
        const int row = gw;
        float x0 = state[lane];
        float x1 = 0.f;
        if      (lane < 4)  x1 = pa[lane];
        else if (lane == 4) x1 = pr[0];
        else if (lane == 5) x1 = ts[0];

        const float4* h04 = (const float4*)h0;
        const float4  hA = h04[lane], hB = h04[64 + lane];
        const float4* wh4 = (const float4*)(Wh + (size_t)row * HDIM);
        const float4 a0 = wh4[lane], a1 = wh4[64 + lane];
        float acc = a0.x*hA.x + a0.y*hA.y + a0.z*hA.z + a0.w*hA.w
                  + a1.x*hB.x + a1.y*hB.y + a1.z*hB.z + a1.w*hB.w;
        const float* wxr = Wx + (size_t)row * 70;
        acc += wxr[lane] * x0;
        if (lane < 6) acc += wxr[64 + lane] * x1;
        acc = wave_sum(acc);
        if (lane == 0) ws[PREACT_OFF + row] = acc + b[row];
    }

    // ---- sims sweep: R4/R10 load pattern, results kept in registers --------
    const float4* c4 = (const float4*)cue;
    const float4 cA = c4[lane], cB = c4[64 + lane];
    float minss = INFINITY;

    const float4 inf4 = make_float4(INFINITY, INFINITY, INFINITY, INFINITY);
    float4 r0 = inf4, r1 = inf4, r2 = inf4, r3 = inf4;
    int it = 0;

    const int NG = NROWS / 4;                    // 25000 groups
    for (int g = gw; g < NG; g += nw) {          // 3 or 4 iterations
        const int n = g * 4;
        const float* r = K + (size_t)n * HDIM;
        const float4* p0 = (const float4*)(r);
        const float4* p1 = (const float4*)(r + HDIM);
        const float4* p2 = (const float4*)(r + 2 * HDIM);
        const float4* p3 = (const float4*)(r + 3 * HDIM);
        const float4 a0 = p0[lane], b0 = p0[64 + lane];
        const float4 a1 = p1[lane], b1 = p1[64 + lane];
        const float4 a2 = p2[lane], b2 = p2[64 + lane];
        const float4 a3 = p3[lane], b3 = p3[64 + lane];
        float s0 = d2sum(a0, cA) + d2sum(b0, cB);
        float s1 = d2sum(a1, cA) + d2sum(b1, cB);
        float s2 = d2sum(a2, cA) + d2sum(b2, cB);
        float s3 = d2sum(a3, cA) + d2sum(b3, cB);
        #pragma unroll
        for (int off = 32; off; off >>= 1) {     // 4 independent chains, ILP
            s0 += __shfl_xor(s0, off);
            s1 += __shfl_xor(s1, off);
            s2 += __shfl_xor(s2, off);
            s3 += __shfl_xor(s3, off);
        }
        const float4 res = make_float4(s0, s1, s2, s3);
        if      (it == 0) r0 = res;              // static register save
        else if (it == 1) r1 = res;
        else if (it == 2) r2 = res;
        else              r3 = res;
        ++it;
        minss = fminf(fminf(minss, s0), fminf(fminf(s1, s2), s3));
    }

    minss = wave_min(minss);
    __shared__ float smin4[4];
    __shared__ int   wcnt[4];
    if (lane == 0) smin4[wib] = minss;
    __syncthreads();
    const float bminv = fminf(fminf(smin4[0], smin4[1]),
                              fminf(smin4[2], smin4[3]));
    if (threadIdx.x == 0) ws[BMIN_OFF + blockIdx.x] = bminv;
    const float thr0 = bminv + 30.0f;

    // ---- candidate emission from registers: lane l owns (iter=l>>2, slot=l&3)
    {
        const int qi = lane >> 2, qj = lane & 3;
        const float4 rq = (qi == 0) ? r0 : (qi == 1) ? r1 : (qi == 2) ? r2 : r3;
        const float v  = (qj == 0) ? rq.x : (qj == 1) ? rq.y
                       : (qj == 2) ? rq.z : rq.w;
        const bool valid = (lane < 16) && (gw + qi * nw < NG);
        const bool ok    = valid && (v <= thr0);
        const unsigned long long mask = __ballot(ok);
        const int cnt = (int)__popcll(mask);
        if (lane == 0) wcnt[wib] = cnt;
        __syncthreads();
        int woff = 0;
        #pragma unroll
        for (int w = 0; w < 4; w++) if (w < wib) woff += wcnt[w];
        if (ok) {
            const int pos = (int)__popcll(mask & ((1ull << lane) - 1ull));
            const int row = (gw + qi * nw) * 4 + qj;
            float2* cand = (float2*)(ws + CAND_OFF);
            cand[(blockIdx.x << 6) + woff + pos] =
                make_float2(v, __int_as_float(row));
        }
        if (threadIdx.x == 0)
            ((int*)ws)[CNTL_OFF + blockIdx.x] =
                wcnt[0] + wcnt[1] + wcnt[2] + wcnt[3];
    }

    // ======== no-poll ticket: ONLY the 2048th arriver continues ==============
    __threadfence();                             // release bmin/cnt/cand/preact
    __shared__ int sOld;
    if (threadIdx.x == 0)
        sOld = atomicAdd((int*)ws + TICK_OFF, 1);
    __syncthreads();
    if (sOld != NBLK_A - 1) return;
    __threadfence();                             // acquire all blocks' data

    // ======== finale (256 threads of the winner block) =======================
    const int t = threadIdx.x;

    __shared__ float sred[4];
    __shared__ int   wtot[4];
    __shared__ float surv_s[K_CAP];
    __shared__ int   surv_n[K_CAP];
    __shared__ float sden;
    __shared__ float hl[HDIM];
    __shared__ float logits[4];

    // ---- 1) global min over 2048 block-mins ----
    float mn = INFINITY;
    #pragma unroll
    for (int j = 0; j < NBLK_A / 256; j++)
        mn = fminf(mn, ws[BMIN_OFF + j * 256 + t]);
    mn = wave_min(mn);
    if (lane == 0) sred[wib] = mn;
    __syncthreads();
    const float smin = fminf(fminf(sred[0], sred[1]), fminf(sred[2], sred[3]));
    const float thr = smin + 30.0f;

    // ---- 2) survivor compaction: thread t owns lists [8t, 8t+8) ------------
    const int*    cnts = (const int*)ws + CNTL_OFF;
    const float2* cand = (const float2*)(ws + CAND_OFF);

    int mycnt = 0;
    #pragma unroll
    for (int L = 0; L < 8; L++) {
        const int bidx = 8 * t + L;
        const int c = cnts[bidx];
        for (int e = 0; e < c; e++)
            if (cand[(bidx << 6) + e].x <= thr) mycnt++;
    }
    int inc = mycnt;                             // wave inclusive scan
    #pragma unroll
    for (int off = 1; off < 64; off <<= 1) {
        const int v = __shfl_up(inc, off);
        if (lane >= off) inc += v;
    }
    if (lane == 63) wtot[wib] = inc;
    __syncthreads();
    int base = 0;
    #pragma unroll
    for (int w = 0; w < 4; w++) if (w < wib) base += wtot[w];
    int off2 = base + inc - mycnt;               // exclusive global offset
    #pragma unroll
    for (int L = 0; L < 8; L++) {                // pass 2: identical order
        const int bidx = 8 * t + L;
        const int c = cnts[bidx];
        for (int e = 0; e < c; e++) {
            const float2 ce = cand[(bidx << 6) + e];
            if (ce.x <= thr) {
                if (off2 < K_CAP) {
                    surv_s[off2] = ce.x;
                    surv_n[off2] = __float_as_int(ce.y);
                }
                off2++;
            }
        }
    }
    __syncthreads();
    const int total = wtot[0] + wtot[1] + wtot[2] + wtot[3];
    const int tot = (total < K_CAP) ? total : K_CAP;

    // ---- 3) weights + exact denominator (serial, deterministic order) ----
    if (t == 0) {
        float den = 0.f;
        for (int i = 0; i < tot; i++) {
            const float e = expf(smin - surv_s[i]);  // = exp(sim - smax)
            surv_s[i] = e;
            den += e;
        }
        sden = den;
    }
    __syncthreads();
    const float inv_den = 1.f / sden;

    // ---- 4) m_t + LSTM cell: thread t owns dims t and t+256 ----
    float m0 = 0.f, m1 = 0.f;
    for (int i = 0; i < tot; i++) {
        const float w = surv_s[i];
        const size_t vb = (size_t)surv_n[i] * HDIM;
        m0 += w * V[vb + t];
        m1 += w * V[vb + 256 + t];
    }
    m0 *= inv_den; m1 *= inv_den;

    #pragma unroll
    for (int half = 0; half < 2; half++) {
        const int tt = t + half * 256;
        const float mm = half ? m1 : m0;
        const float pf = ws[PREACT_OFF + tt];
        const float pi = ws[PREACT_OFF + HDIM + tt];
        const float po = ws[PREACT_OFF + 2*HDIM + tt];
        const float prg= ws[PREACT_OFF + 3*HDIM + tt];
        const float pc = ws[PREACT_OFF + 4*HDIM + tt];
        const float f_t = 1.f / (1.f + expf(-pf));
        const float i_t = 1.f / (1.f + expf(-pi));
        const float o_t = 1.f / (1.f + expf(-po));
        const float r_t = 1.f / (1.f + expf(-prg));
        const float chat = tanhf(pc);
        const float ct = f_t * c0[tt] + i_t * chat + r_t * mm;
        const float ht = o_t * tanhf(ct);
        out[517 + tt] = ct;
        out[5 + tt]   = ht;
        hl[tt] = ht;
    }
    __syncthreads();

    if (wib < 4) {       // actor logits, one wave per row
        float acc = 0.f;
        #pragma unroll
        for (int j = 0; j < HDIM; j += 64)
            acc += aw[wib * HDIM + j + lane] * hl[j + lane];
        acc = wave_sum(acc);
        if (lane == 0) logits[wib] = acc + ab[wib];
    }
    if (wib == 0) {      // critic
        float acc = 0.f;
        #pragma unroll
        for (int j = 0; j < HDIM; j += 64)
            acc += cw[j + lane] * hl[j + lane];
        acc = wave_sum(acc);
        if (lane == 0) out[4] = acc + cb[0];
    }
    __syncthreads();

    if (t == 0) {
        const float mx = fmaxf(fmaxf(logits[0], logits[1]),
                               fmaxf(logits[2], logits[3]));
        const float e0 = expf(logits[0] - mx), e1 = expf(logits[1] - mx);
        const float e2 = expf(logits[2] - mx), e3 = expf(logits[3] - mx);
        const float inv = 1.f / (e0 + e1 + e2 + e3);
        out[0] = e0 * inv; out[1] = e1 * inv;
        out[2] = e2 * inv; out[3] = e3 * inv;
    }
}

extern "C" void kernel_launch(void* const* d_in, const int* in_sizes, int n_in,
                              void* d_out, int out_size, void* d_ws, size_t ws_size,
                              hipStream_t stream) {
    const float* state  = (const float*)d_in[0];
    const float* pa     = (const float*)d_in[1];
    const float* pr     = (const float*)d_in[2];
    const float* ts     = (const float*)d_in[3];
    const float* cue    = (const float*)d_in[4];
    const float* keys   = (const float*)d_in[5];
    const float* vals   = (const float*)d_in[6];
    const float* Wx     = (const float*)d_in[7];
    const float* Wh     = (const float*)d_in[8];
    const float* b      = (const float*)d_in[9];
    const float* aw     = (const float*)d_in[10];
    const float* ab     = (const float*)d_in[11];
    const float* cw     = (const float*)d_in[12];
    const float* cb     = (const float*)d_in[13];
    const float* h0     = (const float*)d_in[14];
    const float* c0     = (const float*)d_in[15];
    float* ws  = (float*)d_ws;
    float* out = (float*)d_out;

    // zero the ticket counter (4 bytes) — stream-ordered, graph-capturable
    (void)hipMemsetAsync((int*)ws + TICK_OFF, 0, sizeof(int), stream);

    kF<<<NBLK_A, 256, 0, stream>>>(state, pa, pr, ts, cue, keys, vals,
                                   Wx, Wh, b, aw, ab, cw, cb, h0, c0, ws, out);
}

// Round 12
// 114.085 us; speedup vs baseline: 3.0162x; 3.0162x over previous
//
#include <hip/hip_runtime.h>
#include <math.h>

#define HDIM 512
#define NROWS 100000
#define NBLK_A 2048
#define K_CAP 1024            // max survivors kB keeps (data: ~3)
#define LISTCAP 65536         // global candidate list capacity (data: ~3500)

// ---- workspace layout (float indices) ----
constexpr int SMIN_OFF   = 0;     // [1] int bits: global min ||K-cue||^2 (memset 0x7F)
constexpr int LCNT_OFF   = 1;     // [1] int: candidate list count (memset 0x00)
constexpr int PREACT_OFF = 16;    // [5*HDIM]
constexpr int LIST_OFF   = PREACT_OFF + 5 * HDIM;  // [LISTCAP] float2 {ss,row}

__device__ __forceinline__ float wave_sum(float v) {
    #pragma unroll
    for (int off = 32; off; off >>= 1) v += __shfl_xor(v, off);
    return v;
}
__device__ __forceinline__ float wave_min(float v) {
    #pragma unroll
    for (int off = 32; off; off >>= 1) v = fminf(v, __shfl_xor(v, off));
    return v;
}
__device__ __forceinline__ float d2sum(float4 a, float4 c) {
    float d, s;
    d = a.x - c.x; s  = d * d;
    d = a.y - c.y; s += d * d;
    d = a.z - c.z; s += d * d;
    d = a.w - c.w; s += d * d;
    return s;
}

// ===== kernel A: R10 sweep minus sims store; atomic smin + list append =======
__global__ __launch_bounds__(256)
void kA(const float* __restrict__ state, const float* __restrict__ pa,
        const float* __restrict__ pr, const float* __restrict__ ts,
        const float* __restrict__ cue, const float* __restrict__ K,
        const float* __restrict__ Wx, const float* __restrict__ Wh,
        const float* __restrict__ b, const float* __restrict__ h0,
        float* __restrict__ ws) {
    const int lane = threadIdx.x & 63;
    const int wib  = threadIdx.x >> 6;
    const int gw   = blockIdx.x * 4 + wib;
    const int nw   = NBLK_A * 4;                 // 8192 waves

    // ---- preact rows (first 2560 waves; hides under the BW-bound sweep) ----
    if (gw < 5 * HDIM) {
        const int row = gw;
        float x0 = state[lane];
        float x1 = 0.f;
        if      (lane < 4)  x1 = pa[lane];
        else if (lane == 4) x1 = pr[0];
        else if (lane == 5) x1 = ts[0];

        const float4* h04 = (const float4*)h0;
        const float4  hA = h04[lane], hB = h04[64 + lane];
        const float4* wh4 = (const float4*)(Wh + (size_t)row * HDIM);
        const float4 a0 = wh4[lane], a1 = wh4[64 + lane];
        float acc = a0.x*hA.x + a0.y*hA.y + a0.z*hA.z + a0.w*hA.w
                  + a1.x*hB.x + a1.y*hB.y + a1.z*hB.z + a1.w*hB.w;
        const float* wxr = Wx + (size_t)row * 70;
        acc += wxr[lane] * x0;
        if (lane < 6) acc += wxr[64 + lane] * x1;
        acc = wave_sum(acc);
        if (lane == 0) ws[PREACT_OFF + row] = acc + b[row];
    }

    // ---- sims sweep: R4/R10 load pattern, results kept in registers --------
    const float4* c4 = (const float4*)cue;
    const float4 cA = c4[lane], cB = c4[64 + lane];
    float minss = INFINITY;

    const float4 inf4 = make_float4(INFINITY, INFINITY, INFINITY, INFINITY);
    float4 r0 = inf4, r1 = inf4, r2 = inf4, r3 = inf4;
    int it = 0;

    const int NG = NROWS / 4;                    // 25000 groups
    for (int g = gw; g < NG; g += nw) {          // 3 or 4 iterations
        const int n = g * 4;
        const float* r = K + (size_t)n * HDIM;
        const float4* p0 = (const float4*)(r);
        const float4* p1 = (const float4*)(r + HDIM);
        const float4* p2 = (const float4*)(r + 2 * HDIM);
        const float4* p3 = (const float4*)(r + 3 * HDIM);
        const float4 a0 = p0[lane], b0 = p0[64 + lane];
        const float4 a1 = p1[lane], b1 = p1[64 + lane];
        const float4 a2 = p2[lane], b2 = p2[64 + lane];
        const float4 a3 = p3[lane], b3 = p3[64 + lane];
        float s0 = d2sum(a0, cA) + d2sum(b0, cB);
        float s1 = d2sum(a1, cA) + d2sum(b1, cB);
        float s2 = d2sum(a2, cA) + d2sum(b2, cB);
        float s3 = d2sum(a3, cA) + d2sum(b3, cB);
        #pragma unroll
        for (int off = 32; off; off >>= 1) {     // 4 independent chains, ILP
            s0 += __shfl_xor(s0, off);
            s1 += __shfl_xor(s1, off);
            s2 += __shfl_xor(s2, off);
            s3 += __shfl_xor(s3, off);
        }
        const float4 res = make_float4(s0, s1, s2, s3);
        if      (it == 0) r0 = res;              // static register save
        else if (it == 1) r1 = res;
        else if (it == 2) r2 = res;
        else              r3 = res;
        ++it;
        minss = fminf(fminf(minss, s0), fminf(fminf(s1, s2), s3));
    }

    minss = wave_min(minss);
    __shared__ float smin4[4];
    if (lane == 0) smin4[wib] = minss;
    __syncthreads();
    const float bminv = fminf(fminf(smin4[0], smin4[1]),
                              fminf(smin4[2], smin4[3]));
    if (threadIdx.x == 0)
        atomicMin((int*)ws + SMIN_OFF, __float_as_int(bminv));  // exact (>=0)
    const float thr0 = bminv + 30.0f;            // block-local superset filter

    // ---- candidate emission: lane l<16 owns (iter=l>>2, slot=l&3) ----------
    const int qi = lane >> 2, qj = lane & 3;
    const float4 rq = (qi == 0) ? r0 : (qi == 1) ? r1 : (qi == 2) ? r2 : r3;
    const float v  = (qj == 0) ? rq.x : (qj == 1) ? rq.y
                   : (qj == 2) ? rq.z : rq.w;
    const bool valid = (lane < 16) && (gw + qi * nw < NG);
    const bool ok    = valid && (v <= thr0);
    const unsigned long long mask = __ballot(ok);
    const int cnt = (int)__popcll(mask);
    int base = 0;
    if (lane == 0 && cnt > 0)
        base = atomicAdd((int*)ws + LCNT_OFF, cnt);   // one atomic per wave
    base = __shfl(base, 0);
    if (ok) {
        const int pos = (int)__popcll(mask & ((1ull << lane) - 1ull));
        const int idx = base + pos;
        if (idx < LISTCAP) {
            const int row = (gw + qi * nw) * 4 + qj;
            float2* list = (float2*)(ws + LIST_OFF);
            list[idx] = make_float2(v, __int_as_float(row));
        }
    }
}

// ===== kernel B: ONE 512-thread block — sorted-survivor finale ===============
__global__ __launch_bounds__(512)
void kB(const float* __restrict__ V, const float* __restrict__ c0,
        const float* __restrict__ aw, const float* __restrict__ ab,
        const float* __restrict__ cw, const float* __restrict__ cb,
        float* __restrict__ ws, float* __restrict__ out) {
    const int t    = threadIdx.x;                // 0..511
    const int lane = t & 63;
    const int wib  = t >> 6;                     // 0..7

    __shared__ float surv_s[K_CAP];
    __shared__ int   surv_n[K_CAP];
    __shared__ int   lcnt;
    __shared__ float sden;
    __shared__ float hl[HDIM];
    __shared__ float logits[4];

    if (t == 0) lcnt = 0;
    __syncthreads();

    const float smin = __int_as_float(((const int*)ws)[SMIN_OFF]);
    const float thr  = smin + 30.0f;
    int total = ((const int*)ws)[LCNT_OFF];
    if (total > LISTCAP) total = LISTCAP;
    const float2* list = (const float2*)(ws + LIST_OFF);

    // ---- filter survivors into LDS (order arbitrary; sorted below) ----------
    for (int i = t; i < total; i += 512) {
        const float2 e = list[i];
        if (e.x <= thr) {
            const int s = atomicAdd(&lcnt, 1);
            if (s < K_CAP) {
                surv_s[s] = e.x;
                surv_n[s] = __float_as_int(e.y);
            }
        }
    }
    __syncthreads();
    const int m = (lcnt < K_CAP) ? lcnt : K_CAP;

    // ---- sort by row index + serial denominator (deterministic) -------------
    if (t == 0) {
        for (int i = 1; i < m; i++) {            // insertion sort (m ~ 3)
            const float ks = surv_s[i];
            const int   kn = surv_n[i];
            int j = i - 1;
            while (j >= 0 && surv_n[j] > kn) {
                surv_s[j + 1] = surv_s[j];
                surv_n[j + 1] = surv_n[j];
                j--;
            }
            surv_s[j + 1] = ks;
            surv_n[j + 1] = kn;
        }
        float den = 0.f;
        for (int i = 0; i < m; i++) {
            const float e = expf(smin - surv_s[i]);   // = exp(sim - smax)
            surv_s[i] = e;
            den += e;
        }
        sden = den;
    }
    __syncthreads();
    const float inv_den = 1.f / sden;

    // ---- m_t + LSTM cell: one thread per dim --------------------------------
    {
        float mm = 0.f;
        for (int i = 0; i < m; i++)
            mm += surv_s[i] * V[(size_t)surv_n[i] * HDIM + t];
        mm *= inv_den;

        const float pf = ws[PREACT_OFF + t];
        const float pi = ws[PREACT_OFF + HDIM + t];
        const float po = ws[PREACT_OFF + 2*HDIM + t];
        const float prg= ws[PREACT_OFF + 3*HDIM + t];
        const float pc = ws[PREACT_OFF + 4*HDIM + t];
        const float f_t = 1.f / (1.f + expf(-pf));
        const float i_t = 1.f / (1.f + expf(-pi));
        const float o_t = 1.f / (1.f + expf(-po));
        const float r_t = 1.f / (1.f + expf(-prg));
        const float chat = tanhf(pc);
        const float ct = f_t * c0[t] + i_t * chat + r_t * mm;
        const float ht = o_t * tanhf(ct);
        out[517 + t] = ct;
        out[5 + t]   = ht;
        hl[t] = ht;
    }
    __syncthreads();

    if (wib < 4) {       // actor logits, one wave per row
        float acc = 0.f;
        #pragma unroll
        for (int j = 0; j < HDIM; j += 64)
            acc += aw[wib * HDIM + j + lane] * hl[j + lane];
        acc = wave_sum(acc);
        if (lane == 0) logits[wib] = acc + ab[wib];
    }
    if (wib == 4) {      // critic
        float acc = 0.f;
        #pragma unroll
        for (int j = 0; j < HDIM; j += 64)
            acc += cw[j + lane] * hl[j + lane];
        acc = wave_sum(acc);
        if (lane == 0) out[4] = acc + cb[0];
    }
    __syncthreads();

    if (t == 0) {
        const float mx = fmaxf(fmaxf(logits[0], logits[1]),
                               fmaxf(logits[2], logits[3]));
        const float e0 = expf(logits[0] - mx), e1 = expf(logits[1] - mx);
        const float e2 = expf(logits[2] - mx), e3 = expf(logits[3] - mx);
        const float inv = 1.f / (e0 + e1 + e2 + e3);
        out[0] = e0 * inv; out[1] = e1 * inv;
        out[2] = e2 * inv; out[3] = e3 * inv;
    }
}

extern "C" void kernel_launch(void* const* d_in, const int* in_sizes, int n_in,
                              void* d_out, int out_size, void* d_ws, size_t ws_size,
                              hipStream_t stream) {
    const float* state  = (const float*)d_in[0];
    const float* pa     = (const float*)d_in[1];
    const float* pr     = (const float*)d_in[2];
    const float* ts     = (const float*)d_in[3];
    const float* cue    = (const float*)d_in[4];
    const float* keys   = (const float*)d_in[5];
    const float* vals   = (const float*)d_in[6];
    const float* Wx     = (const float*)d_in[7];
    const float* Wh     = (const float*)d_in[8];
    const float* b      = (const float*)d_in[9];
    const float* aw     = (const float*)d_in[10];
    const float* ab     = (const float*)d_in[11];
    const float* cw     = (const float*)d_in[12];
    const float* cb     = (const float*)d_in[13];
    const float* h0     = (const float*)d_in[14];
    const float* c0     = (const float*)d_in[15];
    float* ws  = (float*)d_ws;
    float* out = (float*)d_out;

    // smin := 0x7F7F7F7F (huge positive float, > any real ||K-cue||^2)
    (void)hipMemsetAsync((int*)ws + SMIN_OFF, 0x7F, sizeof(int), stream);
    // list count := 0
    (void)hipMemsetAsync((int*)ws + LCNT_OFF, 0x00, sizeof(int), stream);

    kA<<<NBLK_A, 256, 0, stream>>>(state, pa, pr, ts, cue, keys,
                                   Wx, Wh, b, h0, ws);
    kB<<<1, 512, 0, stream>>>(vals, c0, aw, ab, cw, cb, ws, out);
}

// Round 13
// 67.348 us; speedup vs baseline: 5.1094x; 1.6940x over previous
//
#include <hip/hip_runtime.h>
#include <math.h>

// ============================================================================
// MEASUREMENT ROUND (clean A/B vs round 10): source is BYTE-IDENTICAL to the
// round-10 kernel; the only change is kB launched TWICE (kB is a pure function
// of ws -> idempotent, bit-identical outputs). dur - 54.6 = kB + g.
// ============================================================================

#define HDIM 512
#define NROWS 100000
#define NBLK_A 2048
#define K_CAP 1024           // max survivors kB holds (data: ~3)

// ---- workspace layout (float indices) ----
constexpr int SIMS_OFF   = 0;                        // [NROWS] sims = -||K-cue||^2 (write-only legacy path)
constexpr int BMIN_OFF   = NROWS;                    // [NBLK_A] per-block min ||K-cue||^2
constexpr int CNTL_OFF   = BMIN_OFF + NBLK_A;        // [NBLK_A] int candidate counts
constexpr int CAND_OFF   = CNTL_OFF + NBLK_A;        // [NBLK_A*64] float2 {ss, idx}
constexpr int PREACT_OFF = CAND_OFF + NBLK_A * 128;  // [5*HDIM]

__device__ __forceinline__ float wave_sum(float v) {
    #pragma unroll
    for (int off = 32; off; off >>= 1) v += __shfl_xor(v, off);
    return v;
}
__device__ __forceinline__ float wave_min(float v) {
    #pragma unroll
    for (int off = 32; off; off >>= 1) v = fminf(v, __shfl_xor(v, off));
    return v;
}
__device__ __forceinline__ float d2sum(float4 a, float4 c) {
    float d, s;
    d = a.x - c.x; s  = d * d;
    d = a.y - c.y; s += d * d;
    d = a.z - c.z; s += d * d;
    d = a.w - c.w; s += d * d;
    return s;
}

// ===== kernel A: R4 hot loop (roofline) + register-held candidate emission ===
__global__ __launch_bounds__(256)
void kA(const float* __restrict__ state, const float* __restrict__ pa,
        const float* __restrict__ pr, const float* __restrict__ ts,
        const float* __restrict__ cue, const float* __restrict__ K,
        const float* __restrict__ Wx, const float* __restrict__ Wh,
        const float* __restrict__ b, const float* __restrict__ h0,
        float* __restrict__ ws) {
    const int lane = threadIdx.x & 63;
    const int wib  = threadIdx.x >> 6;
    const int gw   = blockIdx.x * 4 + wib;
    const int nw   = NBLK_A * 4;                 // 8192 waves

    // ---- preact rows (first 2560 waves; hides under the BW-bound sweep) ----
    if (gw < 5 * HDIM) {
        const int row = gw;
        float x0 = state[lane];
        float x1 = 0.f;
        if      (lane < 4)  x1 = pa[lane];
        else if (lane == 4) x1 = pr[0];
        else if (lane == 5) x1 = ts[0];

        const float4* h04 = (const float4*)h0;
        const float4  hA = h04[lane], hB = h04[64 + lane];
        const float4* wh4 = (const float4*)(Wh + (size_t)row * HDIM);
        const float4 a0 = wh4[lane], a1 = wh4[64 + lane];
        float acc = a0.x*hA.x + a0.y*hA.y + a0.z*hA.z + a0.w*hA.w
                  + a1.x*hB.x + a1.y*hB.y + a1.z*hB.z + a1.w*hB.w;
        const float* wxr = Wx + (size_t)row * 70;
        acc += wxr[lane] * x0;
        if (lane < 6) acc += wxr[64 + lane] * x1;
        acc = wave_sum(acc);
        if (lane == 0) ws[PREACT_OFF + row] = acc + b[row];
    }

    // ---- sims sweep: IDENTICAL memory path to round 4 ----
    const float4* c4 = (const float4*)cue;
    const float4 cA = c4[lane], cB = c4[64 + lane];
    float minss = INFINITY;

    const float4 inf4 = make_float4(INFINITY, INFINITY, INFINITY, INFINITY);
    float4 r0 = inf4, r1 = inf4, r2 = inf4, r3 = inf4;  // per-iter results (static idx)
    int it = 0;

    const int NG = NROWS / 4;                    // 25000 groups (NROWS % 4 == 0)
    for (int g = gw; g < NG; g += nw) {          // 3 or 4 iterations
        const int n = g * 4;                     // rows n..n+3
        const float* r = K + (size_t)n * HDIM;
        const float4* p0 = (const float4*)(r);
        const float4* p1 = (const float4*)(r + HDIM);
        const float4* p2 = (const float4*)(r + 2 * HDIM);
        const float4* p3 = (const float4*)(r + 3 * HDIM);
        const float4 a0 = p0[lane], b0 = p0[64 + lane];
        const float4 a1 = p1[lane], b1 = p1[64 + lane];
        const float4 a2 = p2[lane], b2 = p2[64 + lane];
        const float4 a3 = p3[lane], b3 = p3[64 + lane];
        float s0 = d2sum(a0, cA) + d2sum(b0, cB);
        float s1 = d2sum(a1, cA) + d2sum(b1, cB);
        float s2 = d2sum(a2, cA) + d2sum(b2, cB);
        float s3 = d2sum(a3, cA) + d2sum(b3, cB);
        #pragma unroll
        for (int off = 32; off; off >>= 1) {     // 4 independent chains, ILP
            s0 += __shfl_xor(s0, off);
            s1 += __shfl_xor(s1, off);
            s2 += __shfl_xor(s2, off);
            s3 += __shfl_xor(s3, off);
        }
        if (lane == 0) {                         // n%4==0 -> 16B aligned
            *(float4*)&ws[SIMS_OFF + n] = make_float4(-s0, -s1, -s2, -s3);
        }
        const float4 res = make_float4(s0, s1, s2, s3);
        if      (it == 0) r0 = res;              // static register save
        else if (it == 1) r1 = res;
        else if (it == 2) r2 = res;
        else              r3 = res;
        ++it;
        minss = fminf(fminf(minss, s0), fminf(fminf(s1, s2), s3));
    }

    minss = wave_min(minss);
    __shared__ float smin[4];
    __shared__ int   wcnt[4];
    if (lane == 0) smin[wib] = minss;
    __syncthreads();
    const float bminv = fminf(fminf(smin[0], smin[1]),
                              fminf(smin[2], smin[3]));
    if (threadIdx.x == 0) ws[BMIN_OFF + blockIdx.x] = bminv;
    const float thr = bminv + 30.0f;

    // ---- candidate emission from registers: lane l owns (iter=l>>2, slot=l&3)
    const int qi = lane >> 2, qj = lane & 3;
    const float4 rq = (qi == 0) ? r0 : (qi == 1) ? r1 : (qi == 2) ? r2 : r3;
    const float v  = (qj == 0) ? rq.x : (qj == 1) ? rq.y : (qj == 2) ? rq.z : rq.w;
    const bool valid = (lane < 16) && (gw + qi * nw < NG);
    const bool ok    = valid && (v <= thr);
    const unsigned long long mask = __ballot(ok);
    const int cnt = (int)__popcll(mask);
    if (lane == 0) wcnt[wib] = cnt;
    __syncthreads();
    int woff = 0;
    #pragma unroll
    for (int w = 0; w < 4; w++) if (w < wib) woff += wcnt[w];
    if (ok) {
        const int pos = (int)__popcll(mask & ((1ull << lane) - 1ull));
        const int row = (gw + qi * nw) * 4 + qj;
        float2* cand = (float2*)(ws + CAND_OFF);
        cand[(blockIdx.x << 6) + woff + pos] = make_float2(v, __int_as_float(row));
    }
    if (threadIdx.x == 0)
        ((int*)ws)[CNTL_OFF + blockIdx.x] = wcnt[0] + wcnt[1] + wcnt[2] + wcnt[3];
}

// ===== kernel B: ONE 1024-thread block — candidates only (~70 KB total) =====
__global__ __launch_bounds__(1024)
void kB(const float* __restrict__ V, const float* __restrict__ c0,
        const float* __restrict__ aw, const float* __restrict__ ab,
        const float* __restrict__ cw, const float* __restrict__ cb,
        float* __restrict__ ws, float* __restrict__ out) {
    const int t    = threadIdx.x;                // 0..1023
    const int lane = t & 63;
    const int wib  = t >> 6;                     // 0..15

    __shared__ float sred[16];
    __shared__ int   wtot[16];
    __shared__ int   stot;
    __shared__ float surv_s[K_CAP];
    __shared__ int   surv_n[K_CAP];
    __shared__ float sden;
    __shared__ float hl[HDIM];
    __shared__ float logits[4];

    // ---- 1) global min over 2048 block-mins ----
    float mn = fminf(ws[BMIN_OFF + t], ws[BMIN_OFF + 1024 + t]);
    mn = wave_min(mn);
    if (lane == 0) sred[wib] = mn;
    __syncthreads();
    float smin = sred[0];
    #pragma unroll
    for (int w = 1; w < 16; w++) smin = fminf(smin, sred[w]);
    const float thr = smin + 30.0f;

    // ---- 2) survivor compaction (two-pass, thread-ordered, deterministic) ---
    const int*    cnts = (const int*)ws + CNTL_OFF;
    const float2* cand = (const float2*)(ws + CAND_OFF);

    int mycnt = 0;
    #pragma unroll
    for (int L = 0; L < 2; L++) {                // lists 2t, 2t+1
        const int bidx = 2 * t + L;
        const int c = cnts[bidx];
        for (int e = 0; e < c; e++)
            if (cand[(bidx << 6) + e].x <= thr) mycnt++;
    }
    int inc = mycnt;                             // wave inclusive scan
    #pragma unroll
    for (int off = 1; off < 64; off <<= 1) {
        const int v = __shfl_up(inc, off);
        if (lane >= off) inc += v;
    }
    if (lane == 63) wtot[wib] = inc;
    __syncthreads();
    int base = 0;
    #pragma unroll
    for (int w = 0; w < 16; w++) if (w < wib) base += wtot[w];
    int off = base + inc - mycnt;                // exclusive offset
    #pragma unroll
    for (int L = 0; L < 2; L++) {                // pass 2: identical order
        const int bidx = 2 * t + L;
        const int c = cnts[bidx];
        for (int e = 0; e < c; e++) {
            const float2 ce = cand[(bidx << 6) + e];
            if (ce.x <= thr) {
                if (off < K_CAP) {
                    surv_s[off] = ce.x;
                    surv_n[off] = __float_as_int(ce.y);
                }
                off++;
            }
        }
    }
    if (t == 1023) stot = off;                   // total survivors
    __syncthreads();
    const int tot = (stot < K_CAP) ? stot : K_CAP;

    // ---- 3) weights + exact denominator (serial, deterministic order) ----
    if (t == 0) {
        float den = 0.f;
        for (int i = 0; i < tot; i++) {
            const float e = expf(smin - surv_s[i]);  // = exp(sim - smax)
            surv_s[i] = e;
            den += e;
        }
        sden = den;
    }
    __syncthreads();
    const float inv_den = 1.f / sden;

    // ---- 4) m_t + LSTM cell (threads 0..511, one per dim) ----
    if (t < HDIM) {
        float m = 0.f;
        for (int i = 0; i < tot; i++)
            m += surv_s[i] * V[(size_t)surv_n[i] * HDIM + t];
        m *= inv_den;

        const float pf = ws[PREACT_OFF + t];
        const float pi = ws[PREACT_OFF + HDIM + t];
        const float po = ws[PREACT_OFF + 2*HDIM + t];
        const float prg= ws[PREACT_OFF + 3*HDIM + t];
        const float pc = ws[PREACT_OFF + 4*HDIM + t];
        const float f_t = 1.f / (1.f + expf(-pf));
        const float i_t = 1.f / (1.f + expf(-pi));
        const float o_t = 1.f / (1.f + expf(-po));
        const float r_t = 1.f / (1.f + expf(-prg));
        const float chat = tanhf(pc);
        const float ct = f_t * c0[t] + i_t * chat + r_t * m;
        const float ht = o_t * tanhf(ct);
        out[517 + t] = ct;
        out[5 + t]   = ht;
        hl[t] = ht;
    }
    __syncthreads();

    if (wib < 4) {       // actor logits, one wave per row
        float acc = 0.f;
        #pragma unroll
        for (int j = 0; j < HDIM; j += 64)
            acc += aw[wib * HDIM + j + lane] * hl[j + lane];
        acc = wave_sum(acc);
        if (lane == 0) logits[wib] = acc + ab[wib];
    }
    if (wib == 4) {      // critic
        float acc = 0.f;
        #pragma unroll
        for (int j = 0; j < HDIM; j += 64)
            acc += cw[j + lane] * hl[j + lane];
        acc = wave_sum(acc);
        if (lane == 0) out[4] = acc + cb[0];
    }
    __syncthreads();

    if (t == 0) {
        const float mx = fmaxf(fmaxf(logits[0], logits[1]),
                               fmaxf(logits[2], logits[3]));
        const float e0 = expf(logits[0] - mx), e1 = expf(logits[1] - mx);
        const float e2 = expf(logits[2] - mx), e3 = expf(logits[3] - mx);
        const float inv = 1.f / (e0 + e1 + e2 + e3);
        out[0] = e0 * inv; out[1] = e1 * inv;
        out[2] = e2 * inv; out[3] = e3 * inv;
    }
}

extern "C" void kernel_launch(void* const* d_in, const int* in_sizes, int n_in,
                              void* d_out, int out_size, void* d_ws, size_t ws_size,
                              hipStream_t stream) {
    const float* state  = (const float*)d_in[0];
    const float* pa     = (const float*)d_in[1];
    const float* pr     = (const float*)d_in[2];
    const float* ts     = (const float*)d_in[3];
    const float* cue    = (const float*)d_in[4];
    const float* keys   = (const float*)d_in[5];
    const float* vals   = (const float*)d_in[6];
    const float* Wx     = (const float*)d_in[7];
    const float* Wh     = (const float*)d_in[8];
    const float* b      = (const float*)d_in[9];
    const float* aw     = (const float*)d_in[10];
    const float* ab     = (const float*)d_in[11];
    const float* cw     = (const float*)d_in[12];
    const float* cb     = (const float*)d_in[13];
    const float* h0     = (const float*)d_in[14];
    const float* c0     = (const float*)d_in[15];
    float* ws  = (float*)d_ws;
    float* out = (float*)d_out;

    kA<<<NBLK_A, 256, 0, stream>>>(state, pa, pr, ts, cue, keys, Wx, Wh, b, h0, ws);
    // kB launched twice: pure function of ws -> idempotent, bit-identical out.
    // Measurement: dur - 54.6 = kB + g.
    kB<<<1, 1024, 0, stream>>>(vals, c0, aw, ab, cw, cb, ws, out);
    kB<<<1, 1024, 0, stream>>>(vals, c0, aw, ab, cw, cb, ws, out);
}

// Round 14
// 54.749 us; speedup vs baseline: 6.2852x; 1.2301x over previous
//
#include <hip/hip_runtime.h>
#include <math.h>

// ============================================================================
// ROUND 14: single-variable experiment vs round 10/13.
// kA publishes ALL cross-kernel data (bmin, cnt, cand, preact) via device-scope
// atomicExch -> values land CLEAN at the coherent point instead of dirty in 8
// per-XCD L2s. kB (consumer) is byte-identical to round 13, launched once.
// Theory: kB's +13us cold-consumer penalty is remote-dirty-line readback.
// ============================================================================

#define HDIM 512
#define NROWS 100000
#define NBLK_A 2048
#define K_CAP 1024           // max survivors kB holds (data: ~3)

// ---- workspace layout (float indices) ----
constexpr int SIMS_OFF   = 0;                        // [NROWS] dead legacy store (kept: A/B discipline)
constexpr int BMIN_OFF   = NROWS;                    // [NBLK_A] per-block min ||K-cue||^2
constexpr int CNTL_OFF   = BMIN_OFF + NBLK_A;        // [NBLK_A] int candidate counts
constexpr int CAND_OFF   = CNTL_OFF + NBLK_A;        // [NBLK_A*64] float2 {ss, idx}
constexpr int PREACT_OFF = CAND_OFF + NBLK_A * 128;  // [5*HDIM]

__device__ __forceinline__ float wave_sum(float v) {
    #pragma unroll
    for (int off = 32; off; off >>= 1) v += __shfl_xor(v, off);
    return v;
}
__device__ __forceinline__ float wave_min(float v) {
    #pragma unroll
    for (int off = 32; off; off >>= 1) v = fminf(v, __shfl_xor(v, off));
    return v;
}
__device__ __forceinline__ float d2sum(float4 a, float4 c) {
    float d, s;
    d = a.x - c.x; s  = d * d;
    d = a.y - c.y; s += d * d;
    d = a.z - c.z; s += d * d;
    d = a.w - c.w; s += d * d;
    return s;
}

// ===== kernel A: R13 kA with atomic (coherent-point) publication =============
__global__ __launch_bounds__(256)
void kA(const float* __restrict__ state, const float* __restrict__ pa,
        const float* __restrict__ pr, const float* __restrict__ ts,
        const float* __restrict__ cue, const float* __restrict__ K,
        const float* __restrict__ Wx, const float* __restrict__ Wh,
        const float* __restrict__ b, const float* __restrict__ h0,
        float* __restrict__ ws) {
    const int lane = threadIdx.x & 63;
    const int wib  = threadIdx.x >> 6;
    const int gw   = blockIdx.x * 4 + wib;
    const int nw   = NBLK_A * 4;                 // 8192 waves

    // ---- preact rows (first 2560 waves; hides under the BW-bound sweep) ----
    if (gw < 5 * HDIM) {
        const int row = gw;
        float x0 = state[lane];
        float x1 = 0.f;
        if      (lane < 4)  x1 = pa[lane];
        else if (lane == 4) x1 = pr[0];
        else if (lane == 5) x1 = ts[0];

        const float4* h04 = (const float4*)h0;
        const float4  hA = h04[lane], hB = h04[64 + lane];
        const float4* wh4 = (const float4*)(Wh + (size_t)row * HDIM);
        const float4 a0 = wh4[lane], a1 = wh4[64 + lane];
        float acc = a0.x*hA.x + a0.y*hA.y + a0.z*hA.z + a0.w*hA.w
                  + a1.x*hB.x + a1.y*hB.y + a1.z*hB.z + a1.w*hB.w;
        const float* wxr = Wx + (size_t)row * 70;
        acc += wxr[lane] * x0;
        if (lane < 6) acc += wxr[64 + lane] * x1;
        acc = wave_sum(acc);
        if (lane == 0)
            (void)atomicExch(&ws[PREACT_OFF + row], acc + b[row]);  // coherent publish
    }

    // ---- sims sweep: IDENTICAL memory path to round 4/10/13 ----
    const float4* c4 = (const float4*)cue;
    const float4 cA = c4[lane], cB = c4[64 + lane];
    float minss = INFINITY;

    const float4 inf4 = make_float4(INFINITY, INFINITY, INFINITY, INFINITY);
    float4 r0 = inf4, r1 = inf4, r2 = inf4, r3 = inf4;
    int it = 0;

    const int NG = NROWS / 4;                    // 25000 groups
    for (int g = gw; g < NG; g += nw) {          // 3 or 4 iterations
        const int n = g * 4;
        const float* r = K + (size_t)n * HDIM;
        const float4* p0 = (const float4*)(r);
        const float4* p1 = (const float4*)(r + HDIM);
        const float4* p2 = (const float4*)(r + 2 * HDIM);
        const float4* p3 = (const float4*)(r + 3 * HDIM);
        const float4 a0 = p0[lane], b0 = p0[64 + lane];
        const float4 a1 = p1[lane], b1 = p1[64 + lane];
        const float4 a2 = p2[lane], b2 = p2[64 + lane];
        const float4 a3 = p3[lane], b3 = p3[64 + lane];
        float s0 = d2sum(a0, cA) + d2sum(b0, cB);
        float s1 = d2sum(a1, cA) + d2sum(b1, cB);
        float s2 = d2sum(a2, cA) + d2sum(b2, cB);
        float s3 = d2sum(a3, cA) + d2sum(b3, cB);
        #pragma unroll
        for (int off = 32; off; off >>= 1) {     // 4 independent chains, ILP
            s0 += __shfl_xor(s0, off);
            s1 += __shfl_xor(s1, off);
            s2 += __shfl_xor(s2, off);
            s3 += __shfl_xor(s3, off);
        }
        if (lane == 0) {                         // dead store kept (A/B discipline)
            *(float4*)&ws[SIMS_OFF + n] = make_float4(-s0, -s1, -s2, -s3);
        }
        const float4 res = make_float4(s0, s1, s2, s3);
        if      (it == 0) r0 = res;              // static register save
        else if (it == 1) r1 = res;
        else if (it == 2) r2 = res;
        else              r3 = res;
        ++it;
        minss = fminf(fminf(minss, s0), fminf(fminf(s1, s2), s3));
    }

    minss = wave_min(minss);
    __shared__ float smin[4];
    __shared__ int   wcnt[4];
    if (lane == 0) smin[wib] = minss;
    __syncthreads();
    const float bminv = fminf(fminf(smin[0], smin[1]),
                              fminf(smin[2], smin[3]));
    if (threadIdx.x == 0)
        (void)atomicExch(&ws[BMIN_OFF + blockIdx.x], bminv);        // coherent publish
    const float thr = bminv + 30.0f;

    // ---- candidate emission from registers: lane l owns (iter=l>>2, slot=l&3)
    const int qi = lane >> 2, qj = lane & 3;
    const float4 rq = (qi == 0) ? r0 : (qi == 1) ? r1 : (qi == 2) ? r2 : r3;
    const float v  = (qj == 0) ? rq.x : (qj == 1) ? rq.y : (qj == 2) ? rq.z : rq.w;
    const bool valid = (lane < 16) && (gw + qi * nw < NG);
    const bool ok    = valid && (v <= thr);
    const unsigned long long mask = __ballot(ok);
    const int cnt = (int)__popcll(mask);
    if (lane == 0) wcnt[wib] = cnt;
    __syncthreads();
    int woff = 0;
    #pragma unroll
    for (int w = 0; w < 4; w++) if (w < wib) woff += wcnt[w];
    if (ok) {
        const int pos = (int)__popcll(mask & ((1ull << lane) - 1ull));
        const int row = (gw + qi * nw) * 4 + qj;
        // pack {ss, row} little-endian into 64b: low=ss bits, high=row
        const unsigned long long pk =
            ((unsigned long long)(unsigned)row << 32) |
            (unsigned long long)__float_as_uint(v);
        unsigned long long* slot =
            (unsigned long long*)(ws + CAND_OFF) + (blockIdx.x << 6) + woff + pos;
        (void)atomicExch(slot, pk);                                  // coherent publish
    }
    if (threadIdx.x == 0)
        (void)atomicExch((int*)ws + CNTL_OFF + blockIdx.x,
                         wcnt[0] + wcnt[1] + wcnt[2] + wcnt[3]);     // coherent publish
}

// ===== kernel B: BYTE-IDENTICAL to round 13's kB (single launch) =============
__global__ __launch_bounds__(1024)
void kB(const float* __restrict__ V, const float* __restrict__ c0,
        const float* __restrict__ aw, const float* __restrict__ ab,
        const float* __restrict__ cw, const float* __restrict__ cb,
        float* __restrict__ ws, float* __restrict__ out) {
    const int t    = threadIdx.x;                // 0..1023
    const int lane = t & 63;
    const int wib  = t >> 6;                     // 0..15

    __shared__ float sred[16];
    __shared__ int   wtot[16];
    __shared__ int   stot;
    __shared__ float surv_s[K_CAP];
    __shared__ int   surv_n[K_CAP];
    __shared__ float sden;
    __shared__ float hl[HDIM];
    __shared__ float logits[4];

    // ---- 1) global min over 2048 block-mins ----
    float mn = fminf(ws[BMIN_OFF + t], ws[BMIN_OFF + 1024 + t]);
    mn = wave_min(mn);
    if (lane == 0) sred[wib] = mn;
    __syncthreads();
    float smin = sred[0];
    #pragma unroll
    for (int w = 1; w < 16; w++) smin = fminf(smin, sred[w]);
    const float thr = smin + 30.0f;

    // ---- 2) survivor compaction (two-pass, thread-ordered, deterministic) ---
    const int*    cnts = (const int*)ws + CNTL_OFF;
    const float2* cand = (const float2*)(ws + CAND_OFF);

    int mycnt = 0;
    #pragma unroll
    for (int L = 0; L < 2; L++) {                // lists 2t, 2t+1
        const int bidx = 2 * t + L;
        const int c = cnts[bidx];
        for (int e = 0; e < c; e++)
            if (cand[(bidx << 6) + e].x <= thr) mycnt++;
    }
    int inc = mycnt;                             // wave inclusive scan
    #pragma unroll
    for (int off = 1; off < 64; off <<= 1) {
        const int v = __shfl_up(inc, off);
        if (lane >= off) inc += v;
    }
    if (lane == 63) wtot[wib] = inc;
    __syncthreads();
    int base = 0;
    #pragma unroll
    for (int w = 0; w < 16; w++) if (w < wib) base += wtot[w];
    int off = base + inc - mycnt;                // exclusive offset
    #pragma unroll
    for (int L = 0; L < 2; L++) {                // pass 2: identical order
        const int bidx = 2 * t + L;
        const int c = cnts[bidx];
        for (int e = 0; e < c; e++) {
            const float2 ce = cand[(bidx << 6) + e];
            if (ce.x <= thr) {
                if (off < K_CAP) {
                    surv_s[off] = ce.x;
                    surv_n[off] = __float_as_int(ce.y);
                }
                off++;
            }
        }
    }
    if (t == 1023) stot = off;                   // total survivors
    __syncthreads();
    const int tot = (stot < K_CAP) ? stot : K_CAP;

    // ---- 3) weights + exact denominator (serial, deterministic order) ----
    if (t == 0) {
        float den = 0.f;
        for (int i = 0; i < tot; i++) {
            const float e = expf(smin - surv_s[i]);  // = exp(sim - smax)
            surv_s[i] = e;
            den += e;
        }
        sden = den;
    }
    __syncthreads();
    const float inv_den = 1.f / sden;

    // ---- 4) m_t + LSTM cell (threads 0..511, one per dim) ----
    if (t < HDIM) {
        float m = 0.f;
        for (int i = 0; i < tot; i++)
            m += surv_s[i] * V[(size_t)surv_n[i] * HDIM + t];
        m *= inv_den;

        const float pf = ws[PREACT_OFF + t];
        const float pi = ws[PREACT_OFF + HDIM + t];
        const float po = ws[PREACT_OFF + 2*HDIM + t];
        const float prg= ws[PREACT_OFF + 3*HDIM + t];
        const float pc = ws[PREACT_OFF + 4*HDIM + t];
        const float f_t = 1.f / (1.f + expf(-pf));
        const float i_t = 1.f / (1.f + expf(-pi));
        const float o_t = 1.f / (1.f + expf(-po));
        const float r_t = 1.f / (1.f + expf(-prg));
        const float chat = tanhf(pc);
        const float ct = f_t * c0[t] + i_t * chat + r_t * m;
        const float ht = o_t * tanhf(ct);
        out[517 + t] = ct;
        out[5 + t]   = ht;
        hl[t] = ht;
    }
    __syncthreads();

    if (wib < 4) {       // actor logits, one wave per row
        float acc = 0.f;
        #pragma unroll
        for (int j = 0; j < HDIM; j += 64)
            acc += aw[wib * HDIM + j + lane] * hl[j + lane];
        acc = wave_sum(acc);
        if (lane == 0) logits[wib] = acc + ab[wib];
    }
    if (wib == 4) {      // critic
        float acc = 0.f;
        #pragma unroll
        for (int j = 0; j < HDIM; j += 64)
            acc += cw[j + lane] * hl[j + lane];
        acc = wave_sum(acc);
        if (lane == 0) out[4] = acc + cb[0];
    }
    __syncthreads();

    if (t == 0) {
        const float mx = fmaxf(fmaxf(logits[0], logits[1]),
                               fmaxf(logits[2], logits[3]));
        const float e0 = expf(logits[0] - mx), e1 = expf(logits[1] - mx);
        const float e2 = expf(logits[2] - mx), e3 = expf(logits[3] - mx);
        const float inv = 1.f / (e0 + e1 + e2 + e3);
        out[0] = e0 * inv; out[1] = e1 * inv;
        out[2] = e2 * inv; out[3] = e3 * inv;
    }
}

extern "C" void kernel_launch(void* const* d_in, const int* in_sizes, int n_in,
                              void* d_out, int out_size, void* d_ws, size_t ws_size,
                              hipStream_t stream) {
    const float* state  = (const float*)d_in[0];
    const float* pa     = (const float*)d_in[1];
    const float* pr     = (const float*)d_in[2];
    const float* ts     = (const float*)d_in[3];
    const float* cue    = (const float*)d_in[4];
    const float* keys   = (const float*)d_in[5];
    const float* vals   = (const float*)d_in[6];
    const float* Wx     = (const float*)d_in[7];
    const float* Wh     = (const float*)d_in[8];
    const float* b      = (const float*)d_in[9];
    const float* aw     = (const float*)d_in[10];
    const float* ab     = (const float*)d_in[11];
    const float* cw     = (const float*)d_in[12];
    const float* cb     = (const float*)d_in[13];
    const float* h0     = (const float*)d_in[14];
    const float* c0     = (const float*)d_in[15];
    float* ws  = (float*)d_ws;
    float* out = (float*)d_out;

    kA<<<NBLK_A, 256, 0, stream>>>(state, pa, pr, ts, cue, keys, Wx, Wh, b, h0, ws);
    kB<<<1, 1024, 0, stream>>>(vals, c0, aw, ab, cw, cb, ws, out);
}

// Round 15
// 50.719 us; speedup vs baseline: 6.7846x; 1.0795x over previous
//
#include <hip/hip_runtime.h>
#include <math.h>

#define HDIM 512
#define NROWS 100000
#define NBLK_A 2048

// ---- workspace layout (float indices) ----
// slab: per-block top-4 {ss, row_bits} pairs, dense & fixed -> no counters,
// no memset, deterministic slots, 64 KB total.
constexpr int SLAB_OFF   = 0;                     // [NBLK_A*4] float2
constexpr int PREACT_OFF = NBLK_A * 8;            // [5*HDIM] floats

__device__ __forceinline__ float wave_sum(float v) {
    #pragma unroll
    for (int off = 32; off; off >>= 1) v += __shfl_xor(v, off);
    return v;
}
__device__ __forceinline__ float wave_min(float v) {
    #pragma unroll
    for (int off = 32; off; off >>= 1) v = fminf(v, __shfl_xor(v, off));
    return v;
}
__device__ __forceinline__ float d2sum(float4 a, float4 c) {
    float d, s;
    d = a.x - c.x; s  = d * d;
    d = a.y - c.y; s += d * d;
    d = a.z - c.z; s += d * d;
    d = a.w - c.w; s += d * d;
    return s;
}

// ===== kernel A: R4-pattern sweep + per-block top-4 slab emission ============
__global__ __launch_bounds__(256)
void kA(const float* __restrict__ state, const float* __restrict__ pa,
        const float* __restrict__ pr, const float* __restrict__ ts,
        const float* __restrict__ cue, const float* __restrict__ K,
        const float* __restrict__ Wx, const float* __restrict__ Wh,
        const float* __restrict__ b, const float* __restrict__ h0,
        float* __restrict__ ws) {
    const int lane = threadIdx.x & 63;
    const int wib  = threadIdx.x >> 6;
    const int gw   = blockIdx.x * 4 + wib;
    const int nw   = NBLK_A * 4;                 // 8192 waves

    // ---- preact rows (first 2560 waves; hides under the BW-bound sweep) ----
    if (gw < 5 * HDIM) {
        const int row = gw;
        float x0 = state[lane];
        float x1 = 0.f;
        if      (lane < 4)  x1 = pa[lane];
        else if (lane == 4) x1 = pr[0];
        else if (lane == 5) x1 = ts[0];

        const float4* h04 = (const float4*)h0;
        const float4  hA = h04[lane], hB = h04[64 + lane];
        const float4* wh4 = (const float4*)(Wh + (size_t)row * HDIM);
        const float4 a0 = wh4[lane], a1 = wh4[64 + lane];
        float acc = a0.x*hA.x + a0.y*hA.y + a0.z*hA.z + a0.w*hA.w
                  + a1.x*hB.x + a1.y*hB.y + a1.z*hB.z + a1.w*hB.w;
        const float* wxr = Wx + (size_t)row * 70;
        acc += wxr[lane] * x0;
        if (lane < 6) acc += wxr[64 + lane] * x1;
        acc = wave_sum(acc);
        if (lane == 0) ws[PREACT_OFF + row] = acc + b[row];
    }

    // ---- sims sweep: identical load pattern to R4/R10; results in regs -----
    const float4* c4 = (const float4*)cue;
    const float4 cA = c4[lane], cB = c4[64 + lane];

    const float4 inf4 = make_float4(INFINITY, INFINITY, INFINITY, INFINITY);
    float4 r0 = inf4, r1 = inf4, r2 = inf4, r3 = inf4;
    int it = 0;

    const int NG = NROWS / 4;                    // 25000 groups
    for (int g = gw; g < NG; g += nw) {          // 3 or 4 iterations
        const int n = g * 4;
        const float* r = K + (size_t)n * HDIM;
        const float4* p0 = (const float4*)(r);
        const float4* p1 = (const float4*)(r + HDIM);
        const float4* p2 = (const float4*)(r + 2 * HDIM);
        const float4* p3 = (const float4*)(r + 3 * HDIM);
        const float4 a0 = p0[lane], b0 = p0[64 + lane];
        const float4 a1 = p1[lane], b1 = p1[64 + lane];
        const float4 a2 = p2[lane], b2 = p2[64 + lane];
        const float4 a3 = p3[lane], b3 = p3[64 + lane];
        float s0 = d2sum(a0, cA) + d2sum(b0, cB);
        float s1 = d2sum(a1, cA) + d2sum(b1, cB);
        float s2 = d2sum(a2, cA) + d2sum(b2, cB);
        float s3 = d2sum(a3, cA) + d2sum(b3, cB);
        #pragma unroll
        for (int off = 32; off; off >>= 1) {     // 4 independent chains, ILP
            s0 += __shfl_xor(s0, off);
            s1 += __shfl_xor(s1, off);
            s2 += __shfl_xor(s2, off);
            s3 += __shfl_xor(s3, off);
        }
        const float4 res = make_float4(s0, s1, s2, s3);
        if      (it == 0) r0 = res;              // static register save
        else if (it == 1) r1 = res;
        else if (it == 2) r2 = res;
        else              r3 = res;
        ++it;
    }

    // ---- per-block top-4 selection (deterministic) -------------------------
    __shared__ float ssb[64];                    // 64 (ss) values per block
    {
        const int qi = lane >> 2, qj = lane & 3;
        const float4 rq = (qi == 0) ? r0 : (qi == 1) ? r1
                        : (qi == 2) ? r2 : r3;
        const float v  = (qj == 0) ? rq.x : (qj == 1) ? rq.y
                       : (qj == 2) ? rq.z : rq.w;
        const bool valid = (lane < 16) && (gw + qi * nw < NG);
        if (lane < 16) ssb[wib * 16 + lane] = valid ? v : INFINITY;
    }
    __syncthreads();

    if (wib == 0) {                              // wave 0: 64 lanes, 64 values
        const int j   = lane;
        const int w2  = j >> 4, l2 = j & 15;
        const int qi2 = l2 >> 2, qj2 = l2 & 3;
        const int grp = (blockIdx.x * 4 + w2) + qi2 * nw;
        const int myrow = grp * 4 + qj2;         // row for this slot (if valid)
        float x = ssb[j];                        // INF if invalid

        float2* slab = (float2*)(ws + SLAB_OFF) + (size_t)blockIdx.x * 4;
        #pragma unroll
        for (int i = 0; i < 4; i++) {            // extract 4 smallest
            const float m1 = wave_min(x);
            const unsigned long long eq = __ballot(x == m1);
            const int first = __ffsll(eq) - 1;
            const int rsel  = __shfl(myrow, first);
            if (lane == 0) slab[i] = make_float2(m1, __int_as_float(rsel));
            if (lane == first) x = INFINITY;
        }
    }
}

// ===== kernel B: 1 block x 1024 — two dependent cold rounds ==================
__global__ __launch_bounds__(1024)
void kB(const float* __restrict__ V, const float* __restrict__ c0,
        const float* __restrict__ aw, const float* __restrict__ ab,
        const float* __restrict__ cw, const float* __restrict__ cb,
        float* __restrict__ ws, float* __restrict__ out) {
    const int t    = threadIdx.x;                // 0..1023
    const int lane = t & 63;
    const int wib  = t >> 6;                     // 0..15

    __shared__ float sred[16];
    __shared__ int   nsurv;
    __shared__ float surv_s[64];
    __shared__ int   surv_n[64];
    __shared__ float sden;
    __shared__ float mpart[2][HDIM];
    __shared__ float hl[HDIM];
    __shared__ float logits[4];

    if (t == 0) nsurv = 0;

    // ---- round 1: issue ALL independent loads up front ---------------------
    // slab: 8192 entries (64 KB); thread t owns one 64B line = 4 float4s
    const float4* s4 = (const float4*)(ws + SLAB_OFF);
    const float4 q0 = s4[t * 4 + 0];
    const float4 q1 = s4[t * 4 + 1];
    const float4 q2 = s4[t * 4 + 2];
    const float4 q3 = s4[t * 4 + 3];

    float pf = 0.f, pi = 0.f, po = 0.f, prg = 0.f, pc = 0.f, c0v = 0.f;
    if (t < HDIM) {
        pf  = ws[PREACT_OFF + t];
        pi  = ws[PREACT_OFF + HDIM + t];
        po  = ws[PREACT_OFF + 2 * HDIM + t];
        prg = ws[PREACT_OFF + 3 * HDIM + t];
        pc  = ws[PREACT_OFF + 4 * HDIM + t];
        c0v = c0[t];
    }
    float hw[8];                                  // head weights (aw rows / cw)
    if (wib < 4) {
        #pragma unroll
        for (int k = 0; k < 8; k++) hw[k] = aw[wib * HDIM + k * 64 + lane];
    } else if (wib == 4) {
        #pragma unroll
        for (int k = 0; k < 8; k++) hw[k] = cw[k * 64 + lane];
    }

    // ---- smin over all 8192 slab entries ------------------------------------
    float mn = fminf(fminf(q0.x, q0.z), fminf(q1.x, q1.z));
    mn = fminf(mn, fminf(fminf(q2.x, q2.z), fminf(q3.x, q3.z)));
    mn = wave_min(mn);
    if (lane == 0) sred[wib] = mn;
    __syncthreads();
    float smin = sred[0];
    #pragma unroll
    for (int w = 1; w < 16; w++) smin = fminf(smin, sred[w]);
    const float thr = smin + 30.0f;

    // ---- filter -> LDS append (order fixed by sort below) -------------------
    {
        const float ss[8] = {q0.x, q0.z, q1.x, q1.z, q2.x, q2.z, q3.x, q3.z};
        const float rb[8] = {q0.y, q0.w, q1.y, q1.w, q2.y, q2.w, q3.y, q3.w};
        #pragma unroll
        for (int k = 0; k < 8; k++) {
            if (ss[k] <= thr) {
                const int i = atomicAdd(&nsurv, 1);
                if (i < 64) {
                    surv_s[i] = ss[k];
                    surv_n[i] = __float_as_int(rb[k]);
                }
            }
        }
    }
    __syncthreads();
    const int m = (nsurv < 64) ? nsurv : 64;

    // ---- sort by row + serial exact denominator (deterministic) -------------
    if (t == 0) {
        for (int i = 1; i < m; i++) {            // insertion sort (m ~ 3)
            const float ks = surv_s[i];
            const int   kn = surv_n[i];
            int j = i - 1;
            while (j >= 0 && surv_n[j] > kn) {
                surv_s[j + 1] = surv_s[j];
                surv_n[j + 1] = surv_n[j];
                j--;
            }
            surv_s[j + 1] = ks;
            surv_n[j + 1] = kn;
        }
        float den = 0.f;
        for (int i = 0; i < m; i++) {
            const float e = expf(smin - surv_s[i]);  // = exp(sim - smax)
            surv_s[i] = e;
            den += e;
        }
        sden = den;
    }
    __syncthreads();
    const float inv_den = 1.f / sden;

    // ---- round 2: V gather, survivor-parity split over all 1024 threads -----
    {
        const int d = t & (HDIM - 1);
        const int p = t >> 9;                    // 0 or 1
        float acc = 0.f;
        for (int i = p; i < m; i += 2)
            acc += surv_s[i] * V[(size_t)surv_n[i] * HDIM + d];
        mpart[p][d] = acc;
    }
    __syncthreads();

    // ---- LSTM cell (threads 0..511) -----------------------------------------
    if (t < HDIM) {
        const float mm = (mpart[0][t] + mpart[1][t]) * inv_den;
        const float f_t = 1.f / (1.f + expf(-pf));
        const float i_t = 1.f / (1.f + expf(-pi));
        const float o_t = 1.f / (1.f + expf(-po));
        const float r_t = 1.f / (1.f + expf(-prg));
        const float chat = tanhf(pc);
        const float ct = f_t * c0v + i_t * chat + r_t * mm;
        const float ht = o_t * tanhf(ct);
        out[517 + t] = ct;
        out[5 + t]   = ht;
        hl[t] = ht;
    }
    __syncthreads();

    // ---- heads --------------------------------------------------------------
    if (wib < 4) {       // actor logits, one wave per row (weights preloaded)
        float acc = 0.f;
        #pragma unroll
        for (int k = 0; k < 8; k++) acc += hw[k] * hl[k * 64 + lane];
        acc = wave_sum(acc);
        if (lane == 0) logits[wib] = acc + ab[wib];
    }
    if (wib == 4) {      // critic
        float acc = 0.f;
        #pragma unroll
        for (int k = 0; k < 8; k++) acc += hw[k] * hl[k * 64 + lane];
        acc = wave_sum(acc);
        if (lane == 0) out[4] = acc + cb[0];
    }
    __syncthreads();

    if (t == 0) {
        const float mx = fmaxf(fmaxf(logits[0], logits[1]),
                               fmaxf(logits[2], logits[3]));
        const float e0 = expf(logits[0] - mx), e1 = expf(logits[1] - mx);
        const float e2 = expf(logits[2] - mx), e3 = expf(logits[3] - mx);
        const float inv = 1.f / (e0 + e1 + e2 + e3);
        out[0] = e0 * inv; out[1] = e1 * inv;
        out[2] = e2 * inv; out[3] = e3 * inv;
    }
}

extern "C" void kernel_launch(void* const* d_in, const int* in_sizes, int n_in,
                              void* d_out, int out_size, void* d_ws, size_t ws_size,
                              hipStream_t stream) {
    const float* state  = (const float*)d_in[0];
    const float* pa     = (const float*)d_in[1];
    const float* pr     = (const float*)d_in[2];
    const float* ts     = (const float*)d_in[3];
    const float* cue    = (const float*)d_in[4];
    const float* keys   = (const float*)d_in[5];
    const float* vals   = (const float*)d_in[6];
    const float* Wx     = (const float*)d_in[7];
    const float* Wh     = (const float*)d_in[8];
    const float* b      = (const float*)d_in[9];
    const float* aw     = (const float*)d_in[10];
    const float* ab     = (const float*)d_in[11];
    const float* cw     = (const float*)d_in[12];
    const float* cb     = (const float*)d_in[13];
    const float* h0     = (const float*)d_in[14];
    const float* c0     = (const float*)d_in[15];
    float* ws  = (float*)d_ws;
    float* out = (float*)d_out;

    kA<<<NBLK_A, 256, 0, stream>>>(state, pa, pr, ts, cue, keys,
                                   Wx, Wh, b, h0, ws);
    kB<<<1, 1024, 0, stream>>>(vals, c0, aw, ab, cw, cb, ws, out);
}